// Round 1
// baseline (139.183 us; speedup 1.0000x reference)
//
#include <hip/hip_runtime.h>
#include <math.h>

#define Bn 4
#define Nn 4096
#define Kn 64
#define NRBF 18
#define EDGE_F 25   // 18 rbf + 3 dU + 4 quat

struct V3 { float x, y, z; };

__device__ __forceinline__ V3 vsub(V3 a, V3 b){ return {a.x-b.x, a.y-b.y, a.z-b.z}; }
__device__ __forceinline__ V3 vcross(V3 a, V3 b){
    return {a.y*b.z - a.z*b.y, a.z*b.x - a.x*b.z, a.x*b.y - a.y*b.x};
}
__device__ __forceinline__ float vdot(V3 a, V3 b){ return a.x*b.x + a.y*b.y + a.z*b.z; }
__device__ __forceinline__ V3 l2n(V3 a){
    float n = sqrtf(vdot(a,a));
    float inv = 1.0f / fmaxf(n, 1e-12f);
    return {a.x*inv, a.y*inv, a.z*inv};
}
__device__ __forceinline__ float sgn(float x){ return (x > 0.f) ? 1.f : ((x < 0.f) ? -1.f : 0.f); }

// ---------------------------------------------------------------------------
// Kernel 1: per-node work. One thread per (b,n).
//  - dihedral features (6 floats) -> out_node
//  - orientation matrix O (9 floats) -> Otab (workspace), zero at pad rows
// ---------------------------------------------------------------------------
__global__ __launch_bounds__(64) void node_kernel(const float* __restrict__ coords,
                                                  float* __restrict__ out_node,
                                                  float* __restrict__ Otab)
{
    int node = blockIdx.x * 64 + threadIdx.x;
    if (node >= Bn * Nn) return;
    int b = node >> 12;            // N = 4096
    int n = node & (Nn - 1);

    // ---- dihedrals: backbone Xf[t] = coords[b, t/3, t%3, :], t in [0, 3N)
    V3 pt[6];
#pragma unroll
    for (int p = 0; p < 6; ++p) {
        int t = 3*n - 1 + p;
        t = max(0, min(t, 3*Nn - 1));
        const float* xp = coords + ((size_t)(b*Nn + t/3) * 4 + (t % 3)) * 3;
        pt[p] = { xp[0], xp[1], xp[2] };
    }
    V3 U[5];
#pragma unroll
    for (int p = 0; p < 5; ++p) U[p] = l2n(vsub(pt[p+1], pt[p]));

    float cv[3], sv[3];
#pragma unroll
    for (int q = 0; q < 3; ++q) {
        int s = 3*n + q;              // index into padded D of length 3N
        if (s == 0 || s >= 3*Nn - 2) {
            cv[q] = 1.f; sv[q] = 0.f; // D = 0
        } else {
            V3 u2 = U[q], u1 = U[q+1], u0 = U[q+2];
            V3 n2 = l2n(vcross(u2, u1));
            V3 n1 = l2n(vcross(u1, u0));
            float cd = vdot(n2, n1);
            cd = fminf(fmaxf(cd, -1.0f + 1e-7f), 1.0f - 1e-7f);
            float Dang = sgn(vdot(u2, n1)) * acosf(cd);
            cv[q] = cosf(Dang);
            sv[q] = sinf(Dang);
        }
    }
    float* on = out_node + (size_t)node * 6;
    on[0] = cv[0]; on[1] = cv[1]; on[2] = cv[2];
    on[3] = sv[0]; on[4] = sv[1]; on[5] = sv[2];

    // ---- orientation matrix (rows: o1, n2, o1 x n2); valid for n in [1, N-3]
    float O[9];
    if (n >= 1 && n <= Nn - 3) {
        const float* c0 = coords + ((size_t)(b*Nn + n - 1) * 4 + 1) * 3;
        const float* c1 = coords + ((size_t)(b*Nn + n    ) * 4 + 1) * 3;
        const float* c2 = coords + ((size_t)(b*Nn + n + 1) * 4 + 1) * 3;
        V3 p0 = {c0[0], c0[1], c0[2]};
        V3 p1 = {c1[0], c1[1], c1[2]};
        V3 p2 = {c2[0], c2[1], c2[2]};
        V3 u2 = l2n(vsub(p1, p0));   // U[n-1]
        V3 u1 = l2n(vsub(p2, p1));   // U[n]
        V3 n2 = l2n(vcross(u2, u1));
        V3 o1 = l2n(vsub(u2, u1));
        V3 r3 = vcross(o1, n2);      // NOT normalized (matches reference)
        O[0] = o1.x; O[1] = o1.y; O[2] = o1.z;
        O[3] = n2.x; O[4] = n2.y; O[5] = n2.z;
        O[6] = r3.x; O[7] = r3.y; O[8] = r3.z;
    } else {
#pragma unroll
        for (int i = 0; i < 9; ++i) O[i] = 0.f;
    }
    float* op = Otab + (size_t)node * 9;
#pragma unroll
    for (int i = 0; i < 9; ++i) op[i] = O[i];
}

// ---------------------------------------------------------------------------
// Kernel 2: per-edge work. One wave per (b,n), lane = k. 4 waves / block.
// 25 floats/edge staged in LDS, streamed out as float4 (coalesced).
// ---------------------------------------------------------------------------
__global__ __launch_bounds__(256) void edge_kernel(const float* __restrict__ dists,
                                                   const int*   __restrict__ eidx,
                                                   const float* __restrict__ coords,
                                                   const float* __restrict__ Otab,
                                                   float* __restrict__ out_edge)
{
    __shared__ float lds[4][Kn * EDGE_F];   // 4 * 6400 B = 25.6 KB
    int wave = threadIdx.x >> 6;
    int lane = threadIdx.x & 63;
    int node = blockIdx.x * 4 + wave;       // global b*N + n
    int b    = node >> 12;
    int e    = node * Kn + lane;

    float D = dists[e];
    int   j = eidx[e];
    int  jn = b * Nn + j;

    float vals[EDGE_F];

    // ---- RBF: mu_m = 20*m/17, sigma = 20/18
    const float inv_sigma = 18.0f / 20.0f;
#pragma unroll
    for (int m = 0; m < NRBF; ++m) {
        float mu = (20.0f / 17.0f) * (float)m;
        float t  = (D - mu) * inv_sigma;
        vals[m] = expf(-t * t);
    }

    // ---- load O matrices and CA coords
    const float* Omp = Otab + (size_t)node * 9;   // wave-uniform
    float Om[9];
#pragma unroll
    for (int i = 0; i < 9; ++i) Om[i] = Omp[i];

    const float* cnp = coords + ((size_t)node * 4 + 1) * 3;  // wave-uniform
    const float* cjp = coords + ((size_t)jn   * 4 + 1) * 3;  // gather (L2)
    float d0 = cjp[0] - cnp[0];
    float d1 = cjp[1] - cnp[1];
    float d2 = cjp[2] - cnp[2];

    // ---- dU = normalize(Om @ d)
    float v0 = Om[0]*d0 + Om[1]*d1 + Om[2]*d2;
    float v1 = Om[3]*d0 + Om[4]*d1 + Om[5]*d2;
    float v2 = Om[6]*d0 + Om[7]*d1 + Om[8]*d2;
    float nv  = sqrtf(v0*v0 + v1*v1 + v2*v2);
    float inv = 1.0f / fmaxf(nv, 1e-12f);
    vals[18] = v0 * inv; vals[19] = v1 * inv; vals[20] = v2 * inv;

    // ---- R = Om^T @ Oj
    const float* Ojp = Otab + (size_t)jn * 9;     // gather (L2)
    float Oj[9];
#pragma unroll
    for (int i = 0; i < 9; ++i) Oj[i] = Ojp[i];

    float R[3][3];
#pragma unroll
    for (int i = 0; i < 3; ++i)
#pragma unroll
        for (int l = 0; l < 3; ++l)
            R[i][l] = Om[0+i]*Oj[0+l] + Om[3+i]*Oj[3+l] + Om[6+i]*Oj[6+l];

    // ---- quaternion
    float Rxx = R[0][0], Ryy = R[1][1], Rzz = R[2][2];
    float m0 = 0.5f * sqrtf(fabsf(1.f + Rxx - Ryy - Rzz));
    float m1 = 0.5f * sqrtf(fabsf(1.f - Rxx + Ryy - Rzz));
    float m2 = 0.5f * sqrtf(fabsf(1.f - Rxx - Ryy + Rzz));
    float q0 = sgn(R[2][1] - R[1][2]) * m0;
    float q1 = sgn(R[0][2] - R[2][0]) * m1;
    float q2 = sgn(R[1][0] - R[0][1]) * m2;
    float q3 = sqrtf(fmaxf(1.f + Rxx + Ryy + Rzz, 0.f)) * 0.5f;
    float qn  = sqrtf(q0*q0 + q1*q1 + q2*q2 + q3*q3);
    float qiv = 1.0f / fmaxf(qn, 1e-12f);
    vals[21] = q0*qiv; vals[22] = q1*qiv; vals[23] = q2*qiv; vals[24] = q3*qiv;

    // ---- stage to LDS (gcd(25,32)=1 -> 2 lanes/bank, conflict-free)
#pragma unroll
    for (int i = 0; i < EDGE_F; ++i) lds[wave][lane * EDGE_F + i] = vals[i];
    __syncthreads();

    // ---- coalesced float4 stream-out: 1600 floats = 400 float4 per wave
    const float4* l4 = (const float4*)(&lds[wave][0]);
    float4* o4 = (float4*)(out_edge + (size_t)node * (Kn * EDGE_F));
    for (int i = lane; i < (Kn * EDGE_F) / 4; i += 64) o4[i] = l4[i];
}

extern "C" void kernel_launch(void* const* d_in, const int* in_sizes, int n_in,
                              void* d_out, int out_size, void* d_ws, size_t ws_size,
                              hipStream_t stream)
{
    const float* coords = (const float*)d_in[0];   // (B,N,4,3) f32
    const float* dists  = (const float*)d_in[1];   // (B,N,K)   f32
    const int*   eidx   = (const int*)  d_in[2];   // (B,N,K)   i32
    // d_in[3] = mask, unused by outputs

    float* out      = (float*)d_out;
    float* out_node = out;                               // B*N*6
    float* out_edge = out + (size_t)Bn * Nn * 6;         // B*N*K*25
    float* Otab     = (float*)d_ws;                      // B*N*9 floats = 576 KB

    node_kernel<<<(Bn * Nn) / 64, 64, 0, stream>>>(coords, out_node, Otab);
    edge_kernel<<<(Bn * Nn) / 4, 256, 0, stream>>>(dists, eidx, coords, Otab, out_edge);
}

// Round 2
// 135.421 us; speedup vs baseline: 1.0278x; 1.0278x over previous
//
#include <hip/hip_runtime.h>
#include <math.h>

#define Bn 4
#define Nn 4096
#define Kn 64
#define NRBF 18
#define EDGE_F 25   // 18 rbf + 3 dU + 4 quat
#define TABF 12     // packed per-node: O[9] + ca[3]  (48 B, float4-aligned)

struct V3 { float x, y, z; };

__device__ __forceinline__ V3 vsub(V3 a, V3 b){ return {a.x-b.x, a.y-b.y, a.z-b.z}; }
__device__ __forceinline__ V3 vcross(V3 a, V3 b){
    return {a.y*b.z - a.z*b.y, a.z*b.x - a.x*b.z, a.x*b.y - a.y*b.x};
}
__device__ __forceinline__ float vdot(V3 a, V3 b){ return a.x*b.x + a.y*b.y + a.z*b.z; }
__device__ __forceinline__ V3 l2n(V3 a){
    float n = sqrtf(vdot(a,a));
    float inv = 1.0f / fmaxf(n, 1e-12f);
    return {a.x*inv, a.y*inv, a.z*inv};
}
__device__ __forceinline__ float sgn(float x){ return (x > 0.f) ? 1.f : ((x < 0.f) ? -1.f : 0.f); }

// ---------------------------------------------------------------------------
// Kernel 1: per-node work. One thread per (b,n).
//  - dihedral features (6 floats) -> out_node
//  - packed table {O[9], ca[3]} -> tab (workspace), O zero at pad rows
// ---------------------------------------------------------------------------
__global__ __launch_bounds__(256) void node_kernel(const float* __restrict__ coords,
                                                   float* __restrict__ out_node,
                                                   float* __restrict__ tab)
{
    int node = blockIdx.x * 256 + threadIdx.x;
    if (node >= Bn * Nn) return;
    int b = node >> 12;            // N = 4096
    int n = node & (Nn - 1);

    // ---- dihedrals: backbone Xf[t] = coords[b, t/3, t%3, :], t in [0, 3N)
    V3 pt[6];
#pragma unroll
    for (int p = 0; p < 6; ++p) {
        int t = 3*n - 1 + p;
        t = max(0, min(t, 3*Nn - 1));
        const float* xp = coords + ((size_t)(b*Nn + t/3) * 4 + (t % 3)) * 3;
        pt[p] = { xp[0], xp[1], xp[2] };
    }
    V3 U[5];
#pragma unroll
    for (int p = 0; p < 5; ++p) U[p] = l2n(vsub(pt[p+1], pt[p]));

    float cv[3], sv[3];
#pragma unroll
    for (int q = 0; q < 3; ++q) {
        int s = 3*n + q;              // index into padded D of length 3N
        if (s == 0 || s >= 3*Nn - 2) {
            cv[q] = 1.f; sv[q] = 0.f; // D = 0
        } else {
            V3 u2 = U[q], u1 = U[q+1], u0 = U[q+2];
            V3 n2 = l2n(vcross(u2, u1));
            V3 n1 = l2n(vcross(u1, u0));
            float cd = vdot(n2, n1);
            cd = fminf(fmaxf(cd, -1.0f + 1e-7f), 1.0f - 1e-7f);
            float Dang = sgn(vdot(u2, n1)) * acosf(cd);
            cv[q] = cosf(Dang);
            sv[q] = sinf(Dang);
        }
    }
    float* on = out_node + (size_t)node * 6;
    on[0] = cv[0]; on[1] = cv[1]; on[2] = cv[2];
    on[3] = sv[0]; on[4] = sv[1]; on[5] = sv[2];

    // ---- CA of this node (goes into packed table)
    const float* c1 = coords + ((size_t)node * 4 + 1) * 3;
    float cax = c1[0], cay = c1[1], caz = c1[2];

    // ---- orientation matrix (rows: o1, n2, o1 x n2); valid for n in [1, N-3]
    float O[9];
    if (n >= 1 && n <= Nn - 3) {
        const float* c0 = coords + ((size_t)(node - 1) * 4 + 1) * 3;
        const float* c2 = coords + ((size_t)(node + 1) * 4 + 1) * 3;
        V3 p0 = {c0[0], c0[1], c0[2]};
        V3 p1 = {cax,   cay,   caz  };
        V3 p2 = {c2[0], c2[1], c2[2]};
        V3 u2 = l2n(vsub(p1, p0));   // U[n-1]
        V3 u1 = l2n(vsub(p2, p1));   // U[n]
        V3 n2 = l2n(vcross(u2, u1));
        V3 o1 = l2n(vsub(u2, u1));
        V3 r3 = vcross(o1, n2);      // NOT normalized (matches reference)
        O[0] = o1.x; O[1] = o1.y; O[2] = o1.z;
        O[3] = n2.x; O[4] = n2.y; O[5] = n2.z;
        O[6] = r3.x; O[7] = r3.y; O[8] = r3.z;
    } else {
#pragma unroll
        for (int i = 0; i < 9; ++i) O[i] = 0.f;
    }

    // ---- packed table write: 3 x float4 per node, coalesced-ish
    float4* tp = (float4*)(tab + (size_t)node * TABF);
    tp[0] = make_float4(O[0], O[1], O[2], O[3]);
    tp[1] = make_float4(O[4], O[5], O[6], O[7]);
    tp[2] = make_float4(O[8], cax, cay, caz);
}

// ---------------------------------------------------------------------------
// Kernel 2: per-edge work. One wave per (b,n), lane = k. 4 waves / block.
// Gathers are 3 x float4 per lane from the packed table (L2-resident, 768 KB).
// 25 floats/edge staged in LDS, streamed out as float4 (coalesced).
// ---------------------------------------------------------------------------
__global__ __launch_bounds__(256) void edge_kernel(const float* __restrict__ dists,
                                                   const int*   __restrict__ eidx,
                                                   const float4* __restrict__ tab4,
                                                   float* __restrict__ out_edge)
{
    __shared__ float lds[4][Kn * EDGE_F];   // 4 * 6400 B = 25.6 KB
    int wave = threadIdx.x >> 6;
    int lane = threadIdx.x & 63;
    int node = blockIdx.x * 4 + wave;       // global b*N + n
    int b    = node >> 12;
    int e    = node * Kn + lane;

    float D = dists[e];
    int   j = eidx[e];
    int  jn = (b << 12) | j;

    // ---- gathered node j: 3 x float4 (dwordx4)
    float4 t0 = tab4[jn * 3 + 0];
    float4 t1 = tab4[jn * 3 + 1];
    float4 t2 = tab4[jn * 3 + 2];
    // ---- own node: wave-uniform, broadcast-coalesced
    float4 s0 = tab4[node * 3 + 0];
    float4 s1 = tab4[node * 3 + 1];
    float4 s2 = tab4[node * 3 + 2];

    float Om[9] = { s0.x, s0.y, s0.z, s0.w, s1.x, s1.y, s1.z, s1.w, s2.x };
    float Oj[9] = { t0.x, t0.y, t0.z, t0.w, t1.x, t1.y, t1.z, t1.w, t2.x };
    float d0 = t2.y - s2.y;
    float d1 = t2.z - s2.z;
    float d2 = t2.w - s2.w;

    float vals[EDGE_F];

    // ---- RBF: mu_m = 20*m/17, sigma = 20/18
    const float inv_sigma = 18.0f / 20.0f;
#pragma unroll
    for (int m = 0; m < NRBF; ++m) {
        float mu = (20.0f / 17.0f) * (float)m;
        float t  = (D - mu) * inv_sigma;
        vals[m] = __expf(-t * t);
    }

    // ---- dU = normalize(Om @ d)
    float v0 = Om[0]*d0 + Om[1]*d1 + Om[2]*d2;
    float v1 = Om[3]*d0 + Om[4]*d1 + Om[5]*d2;
    float v2 = Om[6]*d0 + Om[7]*d1 + Om[8]*d2;
    float nv  = sqrtf(v0*v0 + v1*v1 + v2*v2);
    float inv = 1.0f / fmaxf(nv, 1e-12f);
    vals[18] = v0 * inv; vals[19] = v1 * inv; vals[20] = v2 * inv;

    // ---- R = Om^T @ Oj
    float R[3][3];
#pragma unroll
    for (int i = 0; i < 3; ++i)
#pragma unroll
        for (int l = 0; l < 3; ++l)
            R[i][l] = Om[0+i]*Oj[0+l] + Om[3+i]*Oj[3+l] + Om[6+i]*Oj[6+l];

    // ---- quaternion
    float Rxx = R[0][0], Ryy = R[1][1], Rzz = R[2][2];
    float m0 = 0.5f * sqrtf(fabsf(1.f + Rxx - Ryy - Rzz));
    float m1 = 0.5f * sqrtf(fabsf(1.f - Rxx + Ryy - Rzz));
    float m2 = 0.5f * sqrtf(fabsf(1.f - Rxx - Ryy + Rzz));
    float q0 = sgn(R[2][1] - R[1][2]) * m0;
    float q1 = sgn(R[0][2] - R[2][0]) * m1;
    float q2 = sgn(R[1][0] - R[0][1]) * m2;
    float q3 = sqrtf(fmaxf(1.f + Rxx + Ryy + Rzz, 0.f)) * 0.5f;
    float qn  = sqrtf(q0*q0 + q1*q1 + q2*q2 + q3*q3);
    float qiv = 1.0f / fmaxf(qn, 1e-12f);
    vals[21] = q0*qiv; vals[22] = q1*qiv; vals[23] = q2*qiv; vals[24] = q3*qiv;

    // ---- stage to LDS (stride 25, gcd(25,32)=1 -> 2 lanes/bank = free)
#pragma unroll
    for (int i = 0; i < EDGE_F; ++i) lds[wave][lane * EDGE_F + i] = vals[i];
    __syncthreads();

    // ---- coalesced float4 stream-out: 1600 floats = 400 float4 per wave
    const float4* l4 = (const float4*)(&lds[wave][0]);
    float4* o4 = (float4*)(out_edge + (size_t)node * (Kn * EDGE_F));
#pragma unroll
    for (int r = 0; r < 400 / 64; ++r) o4[r * 64 + lane] = l4[r * 64 + lane];
    {   // tail: 400 = 6*64 + 16
        int i = 6 * 64 + lane;
        if (lane < 16) o4[i] = l4[i];
    }
}

extern "C" void kernel_launch(void* const* d_in, const int* in_sizes, int n_in,
                              void* d_out, int out_size, void* d_ws, size_t ws_size,
                              hipStream_t stream)
{
    const float* coords = (const float*)d_in[0];   // (B,N,4,3) f32
    const float* dists  = (const float*)d_in[1];   // (B,N,K)   f32
    const int*   eidx   = (const int*)  d_in[2];   // (B,N,K)   i32
    // d_in[3] = mask, unused by outputs

    float* out      = (float*)d_out;
    float* out_node = out;                               // B*N*6
    float* out_edge = out + (size_t)Bn * Nn * 6;         // B*N*K*25
    float* tab      = (float*)d_ws;                      // B*N*12 floats = 768 KB

    node_kernel<<<(Bn * Nn) / 256, 256, 0, stream>>>(coords, out_node, tab);
    edge_kernel<<<(Bn * Nn) / 4, 256, 0, stream>>>(dists, eidx, (const float4*)tab, out_edge);
}

// Round 3
// 135.130 us; speedup vs baseline: 1.0300x; 1.0022x over previous
//
#include <hip/hip_runtime.h>
#include <math.h>

#define Bn 4
#define Nn 4096
#define Kn 64
#define NRBF 18
#define EDGE_F 25   // 18 rbf + 3 dU + 4 quat
#define TABF 12     // packed per-node: O[9] + ca[3]  (48 B, float4-aligned)

struct V3 { float x, y, z; };

__device__ __forceinline__ V3 vsub(V3 a, V3 b){ return {a.x-b.x, a.y-b.y, a.z-b.z}; }
__device__ __forceinline__ V3 vcross(V3 a, V3 b){
    return {a.y*b.z - a.z*b.y, a.z*b.x - a.x*b.z, a.x*b.y - a.y*b.x};
}
__device__ __forceinline__ float vdot(V3 a, V3 b){ return a.x*b.x + a.y*b.y + a.z*b.z; }
__device__ __forceinline__ V3 l2n(V3 a){
    float n = sqrtf(vdot(a,a));
    float inv = 1.0f / fmaxf(n, 1e-12f);
    return {a.x*inv, a.y*inv, a.z*inv};
}
__device__ __forceinline__ float sgn(float x){ return (x > 0.f) ? 1.f : ((x < 0.f) ? -1.f : 0.f); }

// ---------------------------------------------------------------------------
// Kernel 1: per-node work. One thread per (b,n).
//  - dihedral features (6 floats) -> out_node
//  - packed table {O[9], ca[3]} -> tab (workspace), O zero at pad rows
// ---------------------------------------------------------------------------
__global__ __launch_bounds__(256) void node_kernel(const float* __restrict__ coords,
                                                   float* __restrict__ out_node,
                                                   float* __restrict__ tab)
{
    int node = blockIdx.x * 256 + threadIdx.x;
    if (node >= Bn * Nn) return;
    int b = node >> 12;            // N = 4096
    int n = node & (Nn - 1);

    // ---- dihedrals: backbone Xf[t] = coords[b, t/3, t%3, :], t in [0, 3N)
    V3 pt[6];
#pragma unroll
    for (int p = 0; p < 6; ++p) {
        int t = 3*n - 1 + p;
        t = max(0, min(t, 3*Nn - 1));
        const float* xp = coords + ((size_t)(b*Nn + t/3) * 4 + (t % 3)) * 3;
        pt[p] = { xp[0], xp[1], xp[2] };
    }
    V3 U[5];
#pragma unroll
    for (int p = 0; p < 5; ++p) U[p] = l2n(vsub(pt[p+1], pt[p]));

    float cv[3], sv[3];
#pragma unroll
    for (int q = 0; q < 3; ++q) {
        int s = 3*n + q;              // index into padded D of length 3N
        if (s == 0 || s >= 3*Nn - 2) {
            cv[q] = 1.f; sv[q] = 0.f; // D = 0
        } else {
            V3 u2 = U[q], u1 = U[q+1], u0 = U[q+2];
            V3 n2 = l2n(vcross(u2, u1));
            V3 n1 = l2n(vcross(u1, u0));
            float cd = vdot(n2, n1);
            cd = fminf(fmaxf(cd, -1.0f + 1e-7f), 1.0f - 1e-7f);
            float Dang = sgn(vdot(u2, n1)) * acosf(cd);
            cv[q] = cosf(Dang);
            sv[q] = sinf(Dang);
        }
    }
    float* on = out_node + (size_t)node * 6;
    on[0] = cv[0]; on[1] = cv[1]; on[2] = cv[2];
    on[3] = sv[0]; on[4] = sv[1]; on[5] = sv[2];

    // ---- CA of this node (goes into packed table)
    const float* c1 = coords + ((size_t)node * 4 + 1) * 3;
    float cax = c1[0], cay = c1[1], caz = c1[2];

    // ---- orientation matrix (rows: o1, n2, o1 x n2); valid for n in [1, N-3]
    float O[9];
    if (n >= 1 && n <= Nn - 3) {
        const float* c0 = coords + ((size_t)(node - 1) * 4 + 1) * 3;
        const float* c2 = coords + ((size_t)(node + 1) * 4 + 1) * 3;
        V3 p0 = {c0[0], c0[1], c0[2]};
        V3 p1 = {cax,   cay,   caz  };
        V3 p2 = {c2[0], c2[1], c2[2]};
        V3 u2 = l2n(vsub(p1, p0));   // U[n-1]
        V3 u1 = l2n(vsub(p2, p1));   // U[n]
        V3 n2 = l2n(vcross(u2, u1));
        V3 o1 = l2n(vsub(u2, u1));
        V3 r3 = vcross(o1, n2);      // NOT normalized (matches reference)
        O[0] = o1.x; O[1] = o1.y; O[2] = o1.z;
        O[3] = n2.x; O[4] = n2.y; O[5] = n2.z;
        O[6] = r3.x; O[7] = r3.y; O[8] = r3.z;
    } else {
#pragma unroll
        for (int i = 0; i < 9; ++i) O[i] = 0.f;
    }

    // ---- packed table write: 3 x float4 per node
    float4* tp = (float4*)(tab + (size_t)node * TABF);
    tp[0] = make_float4(O[0], O[1], O[2], O[3]);
    tp[1] = make_float4(O[4], O[5], O[6], O[7]);
    tp[2] = make_float4(O[8], cax, cay, caz);
}

// ---------------------------------------------------------------------------
// Kernel 2: per-edge work. One wave per (b,n), lane = k. 4 waves / block.
// No __syncthreads: each wave stages and streams only its own LDS slice.
// Own-node table reads forced scalar (readfirstlane -> s_load_dwordx4).
// ---------------------------------------------------------------------------
__global__ __launch_bounds__(256) void edge_kernel(const float* __restrict__ dists,
                                                   const int*   __restrict__ eidx,
                                                   const float4* __restrict__ tab4,
                                                   float* __restrict__ out_edge)
{
    __shared__ float lds[4][Kn * EDGE_F];   // 4 * 6400 B = 25.6 KB
    int wave = threadIdx.x >> 6;
    int lane = threadIdx.x & 63;
    // node is wave-uniform: force to SGPR so own-node loads become s_load
    int node = __builtin_amdgcn_readfirstlane(blockIdx.x * 4 + wave);
    int b    = node >> 12;
    int e    = node * Kn + lane;

    float D = dists[e];
    int   j = eidx[e];
    int  jn = (b << 12) | j;

    // ---- gathered node j: 3 x dwordx4 (VMEM gather, L2-resident table)
    float4 t0 = tab4[jn * 3 + 0];
    float4 t1 = tab4[jn * 3 + 1];
    float4 t2 = tab4[jn * 3 + 2];
    // ---- own node: uniform pointer -> scalar loads
    const float4* sp = tab4 + (size_t)node * 3;
    float4 s0 = sp[0];
    float4 s1 = sp[1];
    float4 s2 = sp[2];

    float Om[9] = { s0.x, s0.y, s0.z, s0.w, s1.x, s1.y, s1.z, s1.w, s2.x };
    float Oj[9] = { t0.x, t0.y, t0.z, t0.w, t1.x, t1.y, t1.z, t1.w, t2.x };
    float d0 = t2.y - s2.y;
    float d1 = t2.z - s2.z;
    float d2 = t2.w - s2.w;

    float vals[EDGE_F];

    // ---- RBF: mu_m = 20*m/17, sigma = 20/18
    const float inv_sigma = 18.0f / 20.0f;
#pragma unroll
    for (int m = 0; m < NRBF; ++m) {
        float mu = (20.0f / 17.0f) * (float)m;
        float t  = (D - mu) * inv_sigma;
        vals[m] = __expf(-t * t);
    }

    // ---- dU = normalize(Om @ d)  (rsqrt instead of sqrt+max+div)
    float v0 = Om[0]*d0 + Om[1]*d1 + Om[2]*d2;
    float v1 = Om[3]*d0 + Om[4]*d1 + Om[5]*d2;
    float v2 = Om[6]*d0 + Om[7]*d1 + Om[8]*d2;
    float ss  = v0*v0 + v1*v1 + v2*v2;
    float inv = rsqrtf(fmaxf(ss, 1e-24f));
    vals[18] = v0 * inv; vals[19] = v1 * inv; vals[20] = v2 * inv;

    // ---- R = Om^T @ Oj
    float R[3][3];
#pragma unroll
    for (int i = 0; i < 3; ++i)
#pragma unroll
        for (int l = 0; l < 3; ++l)
            R[i][l] = Om[0+i]*Oj[0+l] + Om[3+i]*Oj[3+l] + Om[6+i]*Oj[6+l];

    // ---- quaternion
    float Rxx = R[0][0], Ryy = R[1][1], Rzz = R[2][2];
    float m0 = 0.5f * sqrtf(fabsf(1.f + Rxx - Ryy - Rzz));
    float m1 = 0.5f * sqrtf(fabsf(1.f - Rxx + Ryy - Rzz));
    float m2 = 0.5f * sqrtf(fabsf(1.f - Rxx - Ryy + Rzz));
    float q0 = sgn(R[2][1] - R[1][2]) * m0;
    float q1 = sgn(R[0][2] - R[2][0]) * m1;
    float q2 = sgn(R[1][0] - R[0][1]) * m2;
    float q3 = sqrtf(fmaxf(1.f + Rxx + Ryy + Rzz, 0.f)) * 0.5f;
    float qs  = q0*q0 + q1*q1 + q2*q2 + q3*q3;
    float qiv = rsqrtf(fmaxf(qs, 1e-24f));
    vals[21] = q0*qiv; vals[22] = q1*qiv; vals[23] = q2*qiv; vals[24] = q3*qiv;

    // ---- stage to own wave's LDS slice (stride 25: 2 lanes/bank = free)
#pragma unroll
    for (int i = 0; i < EDGE_F; ++i) lds[wave][lane * EDGE_F + i] = vals[i];
    // no __syncthreads needed: wave-private slice; compiler orders via lgkmcnt

    // ---- coalesced float4 stream-out: 1600 floats = 400 float4 per wave
    const float4* l4 = (const float4*)(&lds[wave][0]);
    float4* o4 = (float4*)(out_edge + (size_t)node * (Kn * EDGE_F));
#pragma unroll
    for (int r = 0; r < 400 / 64; ++r) o4[r * 64 + lane] = l4[r * 64 + lane];
    {   // tail: 400 = 6*64 + 16
        int i = 6 * 64 + lane;
        if (lane < 16) o4[i] = l4[i];
    }
}

extern "C" void kernel_launch(void* const* d_in, const int* in_sizes, int n_in,
                              void* d_out, int out_size, void* d_ws, size_t ws_size,
                              hipStream_t stream)
{
    const float* coords = (const float*)d_in[0];   // (B,N,4,3) f32
    const float* dists  = (const float*)d_in[1];   // (B,N,K)   f32
    const int*   eidx   = (const int*)  d_in[2];   // (B,N,K)   i32
    // d_in[3] = mask, unused by outputs

    float* out      = (float*)d_out;
    float* out_node = out;                               // B*N*6
    float* out_edge = out + (size_t)Bn * Nn * 6;         // B*N*K*25
    float* tab      = (float*)d_ws;                      // B*N*12 floats = 768 KB

    node_kernel<<<(Bn * Nn) / 256, 256, 0, stream>>>(coords, out_node, tab);
    edge_kernel<<<(Bn * Nn) / 4, 256, 0, stream>>>(dists, eidx, (const float4*)tab, out_edge);
}